// Round 7
// baseline (1771.936 us; speedup 1.0000x reference)
//
#include <hip/hip_runtime.h>
#include <stdint.h>

// GRU: B=64, T=1024, I=256, H=256, fp32 in/out, bf16 MFMA compute.
// k_prep: fragmentize 6 weight mats into MFMA B-frag layout; fold biases.
// k_proj: x_m = X@W_m + b'_m (z,r pre-scaled by -log2 e), D-frag 8B chunks.
// k_rnn : 32 blocks x 512 thr (8 waves, 2/SIMD, 256-reg budget); 2 batches
//         per block. Wave owns TWO 16-col n-tiles; all three U-mat B-frags
//         in registers (48 x s16x8). A-frag reads are full-wave BROADCAST
//         ds_read_b128 (lanes (l&15)>=2 mirror rows 0/1 -> their D rows are
//         garbage that never touches real rows 0-1). Gates for all 4
//         outputs (2 rows x 2 n-tiles) computed directly on lanes 0-15 from
//         D-fragments -- no LDS redistribution round-trip. Light barrier
//         (lgkmcnt-only) per step; x prefetched 1 step ahead as u32 pairs.

typedef float  f32x4 __attribute__((ext_vector_type(4)));
typedef short  s16x8 __attribute__((ext_vector_type(8)));
typedef unsigned short u16;

#define MFMA_BF16(a, b, c) __builtin_amdgcn_mfma_f32_16x16x32_bf16((a), (b), (c), 0, 0, 0)
#define L2E 1.4426950408889634f

static __device__ __forceinline__ u16 f2bf(float f) {
  uint32_t u = __float_as_uint(f);
  u += 0x7FFFu + ((u >> 16) & 1u);   // RNE
  return (u16)(u >> 16);
}
static __device__ __forceinline__ uint32_t cvt_pk_bf16(float lo, float hi) {
  uint32_t r;
  asm("v_cvt_pk_bf16_f32 %0, %1, %2" : "=v"(r) : "v"(lo), "v"(hi));
  return r;
}
static __device__ __forceinline__ float fast_exp2(float x) {
#if __has_builtin(__builtin_amdgcn_exp2f)
  return __builtin_amdgcn_exp2f(x);
#else
  return exp2f(x);
#endif
}
static __device__ __forceinline__ float fast_rcp(float x) {
#if __has_builtin(__builtin_amdgcn_rcpf)
  return __builtin_amdgcn_rcpf(x);
#else
  return 1.0f / x;
#endif
}
static __device__ __forceinline__ float tanh_(float x) {
  float ax = fabsf(x);
  float e  = fast_exp2(-2.885390081777927f * ax);   // exp(-2|x|)
  float r  = (1.0f - e) * fast_rcp(1.0f + e);
  return x < 0.0f ? -r : r;
}

// ---- ws layout (bytes) ----
// [0, 786432)          : 6 mats x 8kk x 16n x 64lane x 16B bf16 B-fragments
// [786432, 789504)     : folded biases, 3 x 256 fp32 (unscaled)
// [1MiB, 1MiB + 96MiB) : x projections bf16, [m][t][g][n][lane] 8B chunks
#define WS_BIAS_OFF  786432
#define WS_X_OFF     (1u << 20)

// Fragment convention: kappa(l,i) = (l>>4)*8 + i.
// B-frag (mat,kk,n): lane l slot i = M[32kk + kappa(l,i)][16n + (l&15)]
// A-frag (kk):       lane l slot i = A[l&15][32kk + kappa(l,i)]
// C/D: col = lane&15, row = (lane>>4)*4 + reg   [m89]
// hb2 (rows 0-1 only): value (row r, feature f) -> u16 idx r*256 + f.
//   A-read lane l: 16B at byte (l&1-mirrored row)*512 + (l>>4)*16 + kk*64.

__global__ __launch_bounds__(256) void k_prep(
    const float* __restrict__ Wz, const float* __restrict__ Wr, const float* __restrict__ Wh,
    const float* __restrict__ Uz, const float* __restrict__ Ur, const float* __restrict__ Uh,
    const float* __restrict__ bz, const float* __restrict__ br, const float* __restrict__ bh,
    const float* __restrict__ cz, const float* __restrict__ cr, const float* __restrict__ ch,
    u16* __restrict__ wfrag, float* __restrict__ wbias)
{
  if (blockIdx.x == 192) {   // bias fold block
    int c = threadIdx.x;
    wbias[c]       = bz[c] + cz[c];
    wbias[256 + c] = br[c] + cr[c];
    wbias[512 + c] = bh[c];
    return;
  }
  int tid = blockIdx.x * 256 + threadIdx.x;      // 0..49151
  int mat = tid >> 13;                           // 6 mats x 8192 threads
  int kk  = (tid >> 10) & 7;
  int n   = (tid >> 6) & 15;
  int l   = tid & 63;
  const float* M = (mat == 0) ? Wz : (mat == 1) ? Wr : (mat == 2) ? Wh
                 : (mat == 3) ? Uz : (mat == 4) ? Ur : Uh;
  int col   = n * 16 + (l & 15);
  int kbase = kk * 32 + (l >> 4) * 8;
  uint32_t d[4];
#pragma unroll
  for (int p = 0; p < 4; ++p) {
    u16 lo = f2bf(M[(kbase + 2 * p    ) * 256 + col]);
    u16 hi = f2bf(M[(kbase + 2 * p + 1) * 256 + col]);
    d[p] = (uint32_t)lo | ((uint32_t)hi << 16);
  }
  uint32_t* dst = (uint32_t*)(wfrag + ((size_t)mat * 65536 + (size_t)((kk * 16 + n) * 64 + l) * 8));
  dst[0] = d[0]; dst[1] = d[1]; dst[2] = d[2]; dst[3] = d[3];
}

__global__ __launch_bounds__(256) void k_proj(
    const float* __restrict__ X, const u16* __restrict__ wfrag,
    const float* __restrict__ wbias, u16* __restrict__ xout)
{
  const int t   = blockIdx.x;
  const int tid = threadIdx.x;
  const int l   = tid & 63;
  const int w   = tid >> 6;        // wave = batch group (M-tile)

  // A-fragments straight from global: row b = 16w + (l&15), k = 32kk + (l>>4)*8 + i
  const float* xrow = X + ((size_t)(w * 16 + (l & 15)) * 1024 + t) * 256 + (l >> 4) * 8;
  s16x8 af[8];
#pragma unroll
  for (int kk = 0; kk < 8; ++kk) {
    f32x4 a0 = *(const f32x4*)(xrow + kk * 32);
    f32x4 a1 = *(const f32x4*)(xrow + kk * 32 + 4);
    union { uint32_t d[4]; s16x8 v; } U;
    U.d[0] = cvt_pk_bf16(a0[0], a0[1]);
    U.d[1] = cvt_pk_bf16(a0[2], a0[3]);
    U.d[2] = cvt_pk_bf16(a1[0], a1[1]);
    U.d[3] = cvt_pk_bf16(a1[2], a1[3]);
    af[kk] = U.v;
  }

  const s16x8* WB = (const s16x8*)wfrag;
  const int g = w;
#pragma unroll
  for (int m = 0; m < 3; ++m) {
    f32x4 acc[16];
#pragma unroll
    for (int n = 0; n < 16; ++n) acc[n] = 0.0f;
#pragma unroll
    for (int kk = 0; kk < 8; ++kk) {
#pragma unroll
      for (int n = 0; n < 16; ++n) {
        s16x8 bf = WB[(size_t)m * 8192 + (kk * 16 + n) * 64 + l];
        acc[n] = MFMA_BF16(af[kk], bf, acc[n]);
      }
    }
    const float scale = (m < 2) ? -L2E : 1.0f;   // pre-scale z,r by -log2(e)
#pragma unroll
    for (int n = 0; n < 16; ++n) {
      int col = n * 16 + (l & 15);
      float b = wbias[m * 256 + col];
      float v0 = (acc[n][0] + b) * scale;
      float v1 = (acc[n][1] + b) * scale;
      float v2 = (acc[n][2] + b) * scale;
      float v3 = (acc[n][3] + b) * scale;
      uint32_t w0 = cvt_pk_bf16(v0, v1);
      uint32_t w1 = cvt_pk_bf16(v2, v3);
      size_t idx = ((((size_t)m * 1024 + t) * 4 + g) * 16 + n) * 64 + l;
      ((uint64_t*)xout)[idx] = (uint64_t)w0 | ((uint64_t)w1 << 32);
    }
  }
}

__global__ __launch_bounds__(512, 2) void k_rnn(
    const u16* __restrict__ wfrag, const u16* __restrict__ xin,
    const float* __restrict__ h0, const float* __restrict__ ch,
    float* __restrict__ out)
{
  __shared__ __align__(16) u16 hb2[2][512];   // 2 x 1 KiB: h rows 0-1, idx r*256+f

  const int blk = blockIdx.x;           // 0..31 ; batches 2*blk, 2*blk+1
  const int tid = threadIdx.x;
  const int l   = tid & 63;
  const int w   = tid >> 6;             // wave 0..7 owns cols [32w, 32w+32)
  const int col16 = l & 15;

  const s16x8* WB = (const s16x8*)wfrag;

  // All three U-mat B-frags for n-tiles 2w, 2w+1 in registers
  s16x8 BZ[2][8], BR[2][8], BH[2][8];
#pragma unroll
  for (int nt = 0; nt < 2; ++nt) {
    int n = 2 * w + nt;
#pragma unroll
    for (int kk = 0; kk < 8; ++kk) {
      BZ[nt][kk] = WB[(size_t)3 * 8192 + (kk * 16 + n) * 64 + l];
      BR[nt][kk] = WB[(size_t)4 * 8192 + (kk * 16 + n) * 64 + l];
      BH[nt][kk] = WB[(size_t)5 * 8192 + (kk * 16 + n) * 64 + l];
    }
  }

  // gate-lane state: lanes 0-15 own 4 outputs (rg in {0,1} x nt in {0,1})
  // addresses computed with col16 so all lanes stay in-bounds.
  float chv[2], hp[2][2];
#pragma unroll
  for (int nt = 0; nt < 2; ++nt) {
    chv[nt] = ch[32 * w + 16 * nt + col16];
#pragma unroll
    for (int rg = 0; rg < 2; ++rg)
      hp[rg][nt] = h0[(size_t)(2 * blk + rg) * 256 + 32 * w + 16 * nt + col16];
  }

  // seed hb2[0]: 512 threads cover 2 rows x 256 features
  {
    int r = tid >> 8, f = tid & 255;
    hb2[0][r * 256 + f] = f2bf(h0[(size_t)(2 * blk + r) * 256 + f]);
  }
  __syncthreads();

  // A-read: broadcast-mirror address (rows >=2 read row 0/1 -> garbage D rows)
  char* hbbase = (char*)&hb2[0][0];
  const int rd_off = (col16 & 1) * 512 + (l >> 4) * 16;
  const int wb0    = 2 * (32 * w + col16);     // hb write byte for (rg=0, nt=0)

  // x as u32 pairs (both rg values in one load): u32 idx
  const uint32_t* x32 = (const uint32_t*)xin;
  uint32_t xo = (uint32_t)(((blk >> 3) * 16 + 2 * w) * 64 + ((blk & 7) >> 1) * 16 + col16) * 2u
              + (uint32_t)(blk & 1);
  uint32_t oo = (uint32_t)(2 * blk) * 262144u + (uint32_t)(32 * w + col16);

  // prefetch t=0
  uint32_t nx[3][2];
#pragma unroll
  for (int m = 0; m < 3; ++m) {
    nx[m][0] = x32[xo + (uint32_t)m * 8388608u];
    nx[m][1] = x32[xo + (uint32_t)m * 8388608u + 128u];
  }

  int hoff = 0;

  for (int t = 0; t < 1024; ++t) {
    uint32_t cx[3][2];
#pragma unroll
    for (int m = 0; m < 3; ++m) { cx[m][0] = nx[m][0]; cx[m][1] = nx[m][1]; }
    // prefetch t+1 (clamped on last iter)
    xo += (t < 1023) ? 8192u : 0u;
#pragma unroll
    for (int m = 0; m < 3; ++m) {
      nx[m][0] = x32[xo + (uint32_t)m * 8388608u];
      nx[m][1] = x32[xo + (uint32_t)m * 8388608u + 128u];
    }

    const char* rdp = hbbase + hoff + rd_off;

    // ---- MFMA: 3 mats x 2 n-tiles x 8 kk, broadcast A reads ----
    f32x4 az[2], ar[2], ah[2];
#pragma unroll
    for (int nt = 0; nt < 2; ++nt) { az[nt] = 0.0f; ar[nt] = 0.0f; ah[nt] = 0.0f; }
#pragma unroll
    for (int kk = 0; kk < 8; ++kk) {
      s16x8 a_ = *(const s16x8*)(rdp + kk * 64);
      az[0] = MFMA_BF16(a_, BZ[0][kk], az[0]);
      ar[0] = MFMA_BF16(a_, BR[0][kk], ar[0]);
      ah[0] = MFMA_BF16(a_, BH[0][kk], ah[0]);
      az[1] = MFMA_BF16(a_, BZ[1][kk], az[1]);
      ar[1] = MFMA_BF16(a_, BR[1][kk], ar[1]);
      ah[1] = MFMA_BF16(a_, BH[1][kk], ah[1]);
    }

    // ---- gates: lanes 0-15 compute 4 outputs each, straight from D-frags ----
    if (l < 16) {
      char* hbw = hbbase + (hoff ^ 1024) + wb0;
#pragma unroll
      for (int rg = 0; rg < 2; ++rg) {
#pragma unroll
        for (int nt = 0; nt < 2; ++nt) {
          uint32_t xzu = rg ? (cx[0][nt] & 0xffff0000u) : (cx[0][nt] << 16);
          uint32_t xru = rg ? (cx[1][nt] & 0xffff0000u) : (cx[1][nt] << 16);
          uint32_t xhu = rg ? (cx[2][nt] & 0xffff0000u) : (cx[2][nt] << 16);
          float z_  = fast_rcp(1.0f + fast_exp2(fmaf(az[nt][rg], -L2E, __uint_as_float(xzu))));
          float rgt = fast_rcp(1.0f + fast_exp2(fmaf(ar[nt][rg], -L2E, __uint_as_float(xru))));
          float th  = tanh_(fmaf(rgt, ah[nt][rg] + chv[nt], __uint_as_float(xhu)));
          float hn  = fmaf(z_, hp[rg][nt] - th, th);
          hp[rg][nt] = hn;
          out[oo + (uint32_t)rg * 262144u + (uint32_t)nt * 16u] = hn;
          *(u16*)(hbw + rg * 512 + nt * 32) = f2bf(hn);
        }
      }
    }
    oo += 256u;

    hoff ^= 1024;
    // light barrier: LDS ordering only; out-stores stay in flight
    asm volatile("s_waitcnt lgkmcnt(0)" ::: "memory");
    __builtin_amdgcn_s_barrier();
  }

  // h_last
  if (l < 16) {
#pragma unroll
    for (int rg = 0; rg < 2; ++rg)
#pragma unroll
      for (int nt = 0; nt < 2; ++nt)
        out[16777216u + (uint32_t)(2 * blk + rg) * 256u
            + (uint32_t)(32 * w + 16 * nt + col16)] = hp[rg][nt];
  }
}

extern "C" void kernel_launch(void* const* d_in, const int* in_sizes, int n_in,
                              void* d_out, int out_size, void* d_ws, size_t ws_size,
                              hipStream_t stream) {
  const float* X  = (const float*)d_in[0];
  const float* h0 = (const float*)d_in[1];
  const float* Wz = (const float*)d_in[2];
  const float* Wr = (const float*)d_in[3];
  const float* Wh = (const float*)d_in[4];
  const float* bz = (const float*)d_in[5];
  const float* br = (const float*)d_in[6];
  const float* bh = (const float*)d_in[7];
  const float* Uz = (const float*)d_in[8];
  const float* Ur = (const float*)d_in[9];
  const float* Uh = (const float*)d_in[10];
  const float* cz = (const float*)d_in[11];
  const float* cr = (const float*)d_in[12];
  const float* ch = (const float*)d_in[13];

  char*  ws    = (char*)d_ws;
  u16*   wfrag = (u16*)ws;
  float* wbias = (float*)(ws + WS_BIAS_OFF);
  u16*   xbuf  = (u16*)(ws + WS_X_OFF);
  float* out   = (float*)d_out;

  k_prep<<<193, 256, 0, stream>>>(Wz, Wr, Wh, Uz, Ur, Uh, bz, br, bh, cz, cr, ch,
                                  wfrag, wbias);
  k_proj<<<1024, 256, 0, stream>>>(X, wfrag, wbias, xbuf);
  k_rnn<<<32, 512, 0, stream>>>(wfrag, xbuf, h0, ch, out);
}

// Round 8
// 1687.800 us; speedup vs baseline: 1.0498x; 1.0498x over previous
//
#include <hip/hip_runtime.h>
#include <stdint.h>

// GRU: B=64, T=1024, I=256, H=256, fp32 in/out, bf16 MFMA compute.
// k_prep: fragmentize 6 weight mats into MFMA B-frag layout; fold biases.
// k_proj: x_m = X@W_m + b'_m (z,r pre-scaled by -log2 e), D-frag 8B chunks.
// k_rnn : 64 blocks x 256 thr (4 waves, 1/SIMD -> 512-reg unified budget);
//         ONE batch per block. All lanes read the SAME row-0 h fragment
//         (4 addrs, 16-way broadcast, conflict-free) -> all 16 D rows are
//         identical -> every lane holds its own column's gate preact in
//         acc[0]. Wave owns FOUR 16-col n-tiles; all 3 U mats resident
//         (96 s16x8 ~ AGPRs). Lane picks its tile via cndmask; 1 gate/lane,
//         no redistribution. LDS/step ~ 8 bcast reads + 1 b16 write.
//         Light barrier (lgkmcnt-only); x prefetched 2 steps ahead.

typedef float  f32x4 __attribute__((ext_vector_type(4)));
typedef short  s16x8 __attribute__((ext_vector_type(8)));
typedef unsigned short u16;

#define MFMA_BF16(a, b, c) __builtin_amdgcn_mfma_f32_16x16x32_bf16((a), (b), (c), 0, 0, 0)
#define L2E 1.4426950408889634f

static __device__ __forceinline__ u16 f2bf(float f) {
  uint32_t u = __float_as_uint(f);
  u += 0x7FFFu + ((u >> 16) & 1u);   // RNE
  return (u16)(u >> 16);
}
static __device__ __forceinline__ uint32_t cvt_pk_bf16(float lo, float hi) {
  uint32_t r;
  asm("v_cvt_pk_bf16_f32 %0, %1, %2" : "=v"(r) : "v"(lo), "v"(hi));
  return r;
}
static __device__ __forceinline__ float fast_exp2(float x) {
#if __has_builtin(__builtin_amdgcn_exp2f)
  return __builtin_amdgcn_exp2f(x);
#else
  return exp2f(x);
#endif
}
static __device__ __forceinline__ float fast_rcp(float x) {
#if __has_builtin(__builtin_amdgcn_rcpf)
  return __builtin_amdgcn_rcpf(x);
#else
  return 1.0f / x;
#endif
}
static __device__ __forceinline__ float tanh_(float x) {
  float ax = fabsf(x);
  float e  = fast_exp2(-2.885390081777927f * ax);   // exp(-2|x|)
  float r  = (1.0f - e) * fast_rcp(1.0f + e);
  return x < 0.0f ? -r : r;
}

// ---- ws layout (bytes) ----
// [0, 786432)          : 6 mats x 8kk x 16n x 64lane x 16B bf16 B-fragments
// [786432, 789504)     : folded biases, 3 x 256 fp32 (unscaled)
// [1MiB, 1MiB + 96MiB) : x projections bf16, [m][t][g][n][lane][j] u16
#define WS_BIAS_OFF  786432
#define WS_X_OFF     (1u << 20)

// Fragment convention: kappa(l,i) = (l>>4)*8 + i.
// B-frag (mat,kk,n): lane l slot i = M[32kk + kappa(l,i)][16n + (l&15)]
// A-frag (kk):       lane l slot i = A[l&15][32kk + kappa(l,i)]
// C/D: col = lane&15, row = (lane>>4)*4 + reg   [m89]
// hb (row 0 only, 512B/buf): u16 idx = feature f; A-read lane l: 16B at
//   (l>>4)*16 + kk*64  (no col16 dependence -> all D rows = row-0 result).

__global__ __launch_bounds__(256) void k_prep(
    const float* __restrict__ Wz, const float* __restrict__ Wr, const float* __restrict__ Wh,
    const float* __restrict__ Uz, const float* __restrict__ Ur, const float* __restrict__ Uh,
    const float* __restrict__ bz, const float* __restrict__ br, const float* __restrict__ bh,
    const float* __restrict__ cz, const float* __restrict__ cr, const float* __restrict__ ch,
    u16* __restrict__ wfrag, float* __restrict__ wbias)
{
  if (blockIdx.x == 192) {   // bias fold block
    int c = threadIdx.x;
    wbias[c]       = bz[c] + cz[c];
    wbias[256 + c] = br[c] + cr[c];
    wbias[512 + c] = bh[c];
    return;
  }
  int tid = blockIdx.x * 256 + threadIdx.x;      // 0..49151
  int mat = tid >> 13;                           // 6 mats x 8192 threads
  int kk  = (tid >> 10) & 7;
  int n   = (tid >> 6) & 15;
  int l   = tid & 63;
  const float* M = (mat == 0) ? Wz : (mat == 1) ? Wr : (mat == 2) ? Wh
                 : (mat == 3) ? Uz : (mat == 4) ? Ur : Uh;
  int col   = n * 16 + (l & 15);
  int kbase = kk * 32 + (l >> 4) * 8;
  uint32_t d[4];
#pragma unroll
  for (int p = 0; p < 4; ++p) {
    u16 lo = f2bf(M[(kbase + 2 * p    ) * 256 + col]);
    u16 hi = f2bf(M[(kbase + 2 * p + 1) * 256 + col]);
    d[p] = (uint32_t)lo | ((uint32_t)hi << 16);
  }
  uint32_t* dst = (uint32_t*)(wfrag + ((size_t)mat * 65536 + (size_t)((kk * 16 + n) * 64 + l) * 8));
  dst[0] = d[0]; dst[1] = d[1]; dst[2] = d[2]; dst[3] = d[3];
}

__global__ __launch_bounds__(256) void k_proj(
    const float* __restrict__ X, const u16* __restrict__ wfrag,
    const float* __restrict__ wbias, u16* __restrict__ xout)
{
  const int t   = blockIdx.x;
  const int tid = threadIdx.x;
  const int l   = tid & 63;
  const int w   = tid >> 6;        // wave = batch group (M-tile)

  // A-fragments straight from global: row b = 16w + (l&15), k = 32kk + (l>>4)*8 + i
  const float* xrow = X + ((size_t)(w * 16 + (l & 15)) * 1024 + t) * 256 + (l >> 4) * 8;
  s16x8 af[8];
#pragma unroll
  for (int kk = 0; kk < 8; ++kk) {
    f32x4 a0 = *(const f32x4*)(xrow + kk * 32);
    f32x4 a1 = *(const f32x4*)(xrow + kk * 32 + 4);
    union { uint32_t d[4]; s16x8 v; } U;
    U.d[0] = cvt_pk_bf16(a0[0], a0[1]);
    U.d[1] = cvt_pk_bf16(a0[2], a0[3]);
    U.d[2] = cvt_pk_bf16(a1[0], a1[1]);
    U.d[3] = cvt_pk_bf16(a1[2], a1[3]);
    af[kk] = U.v;
  }

  const s16x8* WB = (const s16x8*)wfrag;
  const int g = w;
#pragma unroll
  for (int m = 0; m < 3; ++m) {
    f32x4 acc[16];
#pragma unroll
    for (int n = 0; n < 16; ++n) acc[n] = 0.0f;
#pragma unroll
    for (int kk = 0; kk < 8; ++kk) {
#pragma unroll
      for (int n = 0; n < 16; ++n) {
        s16x8 bf = WB[(size_t)m * 8192 + (kk * 16 + n) * 64 + l];
        acc[n] = MFMA_BF16(af[kk], bf, acc[n]);
      }
    }
    const float scale = (m < 2) ? -L2E : 1.0f;   // pre-scale z,r by -log2(e)
#pragma unroll
    for (int n = 0; n < 16; ++n) {
      int col = n * 16 + (l & 15);
      float b = wbias[m * 256 + col];
      float v0 = (acc[n][0] + b) * scale;
      float v1 = (acc[n][1] + b) * scale;
      float v2 = (acc[n][2] + b) * scale;
      float v3 = (acc[n][3] + b) * scale;
      uint32_t w0 = cvt_pk_bf16(v0, v1);
      uint32_t w1 = cvt_pk_bf16(v2, v3);
      size_t idx = ((((size_t)m * 1024 + t) * 4 + g) * 16 + n) * 64 + l;
      ((uint64_t*)xout)[idx] = (uint64_t)w0 | ((uint64_t)w1 << 32);
    }
  }
}

__global__ __launch_bounds__(256, 1) void k_rnn(
    const u16* __restrict__ wfrag, const u16* __restrict__ xin,
    const float* __restrict__ h0, const float* __restrict__ ch,
    float* __restrict__ out)
{
  __shared__ __align__(16) u16 hb[2][256];   // 2 x 512B: h row 0, dbuf

  const int b   = blockIdx.x;          // 0..63 = batch
  const int tid = threadIdx.x;
  const int l   = tid & 63;
  const int w   = tid >> 6;            // wave 0..3 owns cols [64w, 64w+64)
  const int col16 = l & 15;
  const int ntq   = l >> 4;            // this lane's n-tile within wave
  const int cgate = w * 64 + l;        // == w*64 + ntq*16 + col16

  const s16x8* WB = (const s16x8*)wfrag;

  // All three U mats' B-frags for n-tiles 4w..4w+3 (96 s16x8 -> AGPRs)
  s16x8 BZ[4][8], BR[4][8], BH[4][8];
#pragma unroll
  for (int q = 0; q < 4; ++q) {
    int n = 4 * w + q;
#pragma unroll
    for (int kk = 0; kk < 8; ++kk) {
      BZ[q][kk] = WB[(size_t)3 * 8192 + (kk * 16 + n) * 64 + l];
      BR[q][kk] = WB[(size_t)4 * 8192 + (kk * 16 + n) * 64 + l];
      BH[q][kk] = WB[(size_t)5 * 8192 + (kk * 16 + n) * 64 + l];
    }
  }

  const float chv = ch[cgate];
  float hp = h0[(size_t)b * 256 + cgate];

  // seed hb[0]: 256 threads cover 256 features of row 0
  hb[0][tid] = f2bf(h0[(size_t)b * 256 + tid]);
  __syncthreads();

  char* hbbase = (char*)&hb[0][0];
  const int rd_off = ntq * 16;         // + kk*64 + hoff ; no col16 dependence
  const int wb_off = cgate * 2;

  // xbuf u16 index for (m=0, t=0): [m][t][g][n][lane][j]
  const int g  = b >> 4, q4 = (b & 15) >> 2, j = b & 3;
  const int n_ = 4 * w + ntq;
  uint32_t xo = (uint32_t)(((g * 16 + n_) * 64 + q4 * 16 + col16) * 4 + j);
  const uint32_t XM = 16777216u;       // m-stride (u16), t-stride = 16384
  uint32_t oo = (uint32_t)b * 262144u + (uint32_t)cgate;

  // prefetch t=0, t=1 (depth 2)
  u16 xa0 = xin[xo],           xa1 = xin[xo + XM],           xa2 = xin[xo + 2u * XM];
  u16 xb0 = xin[xo + 16384u],  xb1 = xin[xo + 16384u + XM],  xb2 = xin[xo + 16384u + 2u * XM];
  uint32_t xo2 = xo + 32768u;          // t=2

  int hoff = 0;

  for (int t = 0; t < 1024; ++t) {
    u16 x0 = xa0, x1 = xa1, x2 = xa2;
    xa0 = xb0; xa1 = xb1; xa2 = xb2;
    xb0 = xin[xo2]; xb1 = xin[xo2 + XM]; xb2 = xin[xo2 + 2u * XM];
    xo2 += (t < 1021) ? 16384u : 0u;

    const char* rdp = hbbase + hoff + rd_off;

    // ---- MFMA: 3 mats x 4 n-tiles x 8 kk, broadcast A reads ----
    f32x4 az0 = 0.0f, az1 = 0.0f, az2 = 0.0f, az3 = 0.0f;
    f32x4 ar0 = 0.0f, ar1 = 0.0f, ar2 = 0.0f, ar3 = 0.0f;
    f32x4 ah0 = 0.0f, ah1 = 0.0f, ah2 = 0.0f, ah3 = 0.0f;
#pragma unroll
    for (int kk = 0; kk < 8; ++kk) {
      s16x8 a_ = *(const s16x8*)(rdp + kk * 64);
      az0 = MFMA_BF16(a_, BZ[0][kk], az0);
      ar0 = MFMA_BF16(a_, BR[0][kk], ar0);
      ah0 = MFMA_BF16(a_, BH[0][kk], ah0);
      az1 = MFMA_BF16(a_, BZ[1][kk], az1);
      ar1 = MFMA_BF16(a_, BR[1][kk], ar1);
      ah1 = MFMA_BF16(a_, BH[1][kk], ah1);
      az2 = MFMA_BF16(a_, BZ[2][kk], az2);
      ar2 = MFMA_BF16(a_, BR[2][kk], ar2);
      ah2 = MFMA_BF16(a_, BH[2][kk], ah2);
      az3 = MFMA_BF16(a_, BZ[3][kk], az3);
      ar3 = MFMA_BF16(a_, BR[3][kk], ar3);
      ah3 = MFMA_BF16(a_, BH[3][kk], ah3);
    }

    // ---- per-lane tile select (all D rows identical -> reg 0 valid) ----
    float vz = (ntq < 2) ? ((ntq == 0) ? az0[0] : az1[0])
                         : ((ntq == 2) ? az2[0] : az3[0]);
    float vr = (ntq < 2) ? ((ntq == 0) ? ar0[0] : ar1[0])
                         : ((ntq == 2) ? ar2[0] : ar3[0]);
    float vh = (ntq < 2) ? ((ntq == 0) ? ah0[0] : ah1[0])
                         : ((ntq == 2) ? ah2[0] : ah3[0]);

    // ---- gate: exactly 1 output per lane ----
    float xz = __uint_as_float((uint32_t)x0 << 16);
    float xr = __uint_as_float((uint32_t)x1 << 16);
    float xh = __uint_as_float((uint32_t)x2 << 16);

    float z_  = fast_rcp(1.0f + fast_exp2(fmaf(vz, -L2E, xz)));
    float rgt = fast_rcp(1.0f + fast_exp2(fmaf(vr, -L2E, xr)));
    float th  = tanh_(fmaf(rgt, vh + chv, xh));
    float hn  = fmaf(z_, hp - th, th);
    hp = hn;

    // next-step h write + output store (store stays in flight)
    *(u16*)(hbbase + (hoff ^ 512) + wb_off) = f2bf(hn);
    out[oo] = hn;
    oo += 256u;

    hoff ^= 512;
    // light barrier: LDS ordering only; do NOT drain vmcnt
    asm volatile("s_waitcnt lgkmcnt(0)" ::: "memory");
    __builtin_amdgcn_s_barrier();
  }

  // h_last
  out[16777216u + (uint32_t)b * 256u + (uint32_t)cgate] = hp;
}

extern "C" void kernel_launch(void* const* d_in, const int* in_sizes, int n_in,
                              void* d_out, int out_size, void* d_ws, size_t ws_size,
                              hipStream_t stream) {
  const float* X  = (const float*)d_in[0];
  const float* h0 = (const float*)d_in[1];
  const float* Wz = (const float*)d_in[2];
  const float* Wr = (const float*)d_in[3];
  const float* Wh = (const float*)d_in[4];
  const float* bz = (const float*)d_in[5];
  const float* br = (const float*)d_in[6];
  const float* bh = (const float*)d_in[7];
  const float* Uz = (const float*)d_in[8];
  const float* Ur = (const float*)d_in[9];
  const float* Uh = (const float*)d_in[10];
  const float* cz = (const float*)d_in[11];
  const float* cr = (const float*)d_in[12];
  const float* ch = (const float*)d_in[13];

  char*  ws    = (char*)d_ws;
  u16*   wfrag = (u16*)ws;
  float* wbias = (float*)(ws + WS_BIAS_OFF);
  u16*   xbuf  = (u16*)(ws + WS_X_OFF);
  float* out   = (float*)d_out;

  k_prep<<<193, 256, 0, stream>>>(Wz, Wr, Wh, Uz, Ur, Uh, bz, br, bh, cz, cr, ch,
                                  wfrag, wbias);
  k_proj<<<1024, 256, 0, stream>>>(X, wfrag, wbias, xbuf);
  k_rnn<<<64, 256, 0, stream>>>(wfrag, xbuf, h0, ch, out);
}

// Round 9
// 1137.634 us; speedup vs baseline: 1.5576x; 1.4836x over previous
//
#include <hip/hip_runtime.h>
#include <stdint.h>

// GRU: B=64, T=1024, I=256, H=256, fp32 in/out, bf16 MFMA compute.
// k_prep: fragmentize 6 weight mats into MFMA B-frag layout; fold biases.
// k_proj: x_m = X@W_m + b'_m (z,r pre-scaled by -log2 e), D-frag 8B chunks.
// k_rnn : 32 blocks x 512 thr (8 waves, 2/SIMD); 2 batches/block.
//         Parity-mirror A-reads: lane reads h row (col16&1) -> A row i holds
//         h[i&1] -> EVERY lane's acc regs 0/1 = batch0/1 preacts for its own
//         column (bank-free: 2 addrs/bank + 8-way broadcast; R8 measured 0
//         conflicts for the broadcast pattern). Wave owns TWO 16-col
//         n-tiles, all 3 U mats in regs (48 s16x8 -> AGPRs, R6-proven).
//         Uniform 1 gate/lane (rg=l>>5, nt=(l>>4)&1, col=l&15) via cndmask
//         select -- no LDS redistribution, no divergence anywhere in loop.
//         Light barrier (lgkmcnt-only); x as u32 pairs prefetched 1 ahead.

typedef float  f32x4 __attribute__((ext_vector_type(4)));
typedef short  s16x8 __attribute__((ext_vector_type(8)));
typedef unsigned short u16;

#define MFMA_BF16(a, b, c) __builtin_amdgcn_mfma_f32_16x16x32_bf16((a), (b), (c), 0, 0, 0)
#define L2E 1.4426950408889634f

static __device__ __forceinline__ u16 f2bf(float f) {
  uint32_t u = __float_as_uint(f);
  u += 0x7FFFu + ((u >> 16) & 1u);   // RNE
  return (u16)(u >> 16);
}
static __device__ __forceinline__ uint32_t cvt_pk_bf16(float lo, float hi) {
  uint32_t r;
  asm("v_cvt_pk_bf16_f32 %0, %1, %2" : "=v"(r) : "v"(lo), "v"(hi));
  return r;
}
static __device__ __forceinline__ float fast_exp2(float x) {
#if __has_builtin(__builtin_amdgcn_exp2f)
  return __builtin_amdgcn_exp2f(x);
#else
  return exp2f(x);
#endif
}
static __device__ __forceinline__ float fast_rcp(float x) {
#if __has_builtin(__builtin_amdgcn_rcpf)
  return __builtin_amdgcn_rcpf(x);
#else
  return 1.0f / x;
#endif
}
static __device__ __forceinline__ float tanh_(float x) {
  float ax = fabsf(x);
  float e  = fast_exp2(-2.885390081777927f * ax);   // exp(-2|x|)
  float r  = (1.0f - e) * fast_rcp(1.0f + e);
  return x < 0.0f ? -r : r;
}

// ---- ws layout (bytes) ----
// [0, 786432)          : 6 mats x 8kk x 16n x 64lane x 16B bf16 B-fragments
// [786432, 789504)     : folded biases, 3 x 256 fp32 (unscaled)
// [1MiB, 1MiB + 96MiB) : x projections bf16, [m][t][g][n][lane][j] u16
#define WS_BIAS_OFF  786432
#define WS_X_OFF     (1u << 20)

// Fragment convention: kappa(l,i) = (l>>4)*8 + i.
// B-frag (mat,kk,n): lane l slot i = M[32kk + kappa(l,i)][16n + (l&15)]
// A-frag (kk):       lane l slot i = A[l&15][32kk + kappa(l,i)]
// C/D: col = lane&15, row = (lane>>4)*4 + reg   [m89]
// hb (rows 0-1, 1KB/buf): u16 idx = r*256 + f.
//   A-read lane l: 16B at (col16&1)*512 + (l>>4)*16 + kk*64
//   -> A[i] = h[i&1]; D reg j = batch (j&1) preact at col l&15.

__global__ __launch_bounds__(256) void k_prep(
    const float* __restrict__ Wz, const float* __restrict__ Wr, const float* __restrict__ Wh,
    const float* __restrict__ Uz, const float* __restrict__ Ur, const float* __restrict__ Uh,
    const float* __restrict__ bz, const float* __restrict__ br, const float* __restrict__ bh,
    const float* __restrict__ cz, const float* __restrict__ cr, const float* __restrict__ ch,
    u16* __restrict__ wfrag, float* __restrict__ wbias)
{
  if (blockIdx.x == 192) {   // bias fold block
    int c = threadIdx.x;
    wbias[c]       = bz[c] + cz[c];
    wbias[256 + c] = br[c] + cr[c];
    wbias[512 + c] = bh[c];
    return;
  }
  int tid = blockIdx.x * 256 + threadIdx.x;      // 0..49151
  int mat = tid >> 13;                           // 6 mats x 8192 threads
  int kk  = (tid >> 10) & 7;
  int n   = (tid >> 6) & 15;
  int l   = tid & 63;
  const float* M = (mat == 0) ? Wz : (mat == 1) ? Wr : (mat == 2) ? Wh
                 : (mat == 3) ? Uz : (mat == 4) ? Ur : Uh;
  int col   = n * 16 + (l & 15);
  int kbase = kk * 32 + (l >> 4) * 8;
  uint32_t d[4];
#pragma unroll
  for (int p = 0; p < 4; ++p) {
    u16 lo = f2bf(M[(kbase + 2 * p    ) * 256 + col]);
    u16 hi = f2bf(M[(kbase + 2 * p + 1) * 256 + col]);
    d[p] = (uint32_t)lo | ((uint32_t)hi << 16);
  }
  uint32_t* dst = (uint32_t*)(wfrag + ((size_t)mat * 65536 + (size_t)((kk * 16 + n) * 64 + l) * 8));
  dst[0] = d[0]; dst[1] = d[1]; dst[2] = d[2]; dst[3] = d[3];
}

__global__ __launch_bounds__(256) void k_proj(
    const float* __restrict__ X, const u16* __restrict__ wfrag,
    const float* __restrict__ wbias, u16* __restrict__ xout)
{
  const int t   = blockIdx.x;
  const int tid = threadIdx.x;
  const int l   = tid & 63;
  const int w   = tid >> 6;        // wave = batch group (M-tile)

  // A-fragments straight from global: row b = 16w + (l&15), k = 32kk + (l>>4)*8 + i
  const float* xrow = X + ((size_t)(w * 16 + (l & 15)) * 1024 + t) * 256 + (l >> 4) * 8;
  s16x8 af[8];
#pragma unroll
  for (int kk = 0; kk < 8; ++kk) {
    f32x4 a0 = *(const f32x4*)(xrow + kk * 32);
    f32x4 a1 = *(const f32x4*)(xrow + kk * 32 + 4);
    union { uint32_t d[4]; s16x8 v; } U;
    U.d[0] = cvt_pk_bf16(a0[0], a0[1]);
    U.d[1] = cvt_pk_bf16(a0[2], a0[3]);
    U.d[2] = cvt_pk_bf16(a1[0], a1[1]);
    U.d[3] = cvt_pk_bf16(a1[2], a1[3]);
    af[kk] = U.v;
  }

  const s16x8* WB = (const s16x8*)wfrag;
  const int g = w;
#pragma unroll
  for (int m = 0; m < 3; ++m) {
    f32x4 acc[16];
#pragma unroll
    for (int n = 0; n < 16; ++n) acc[n] = 0.0f;
#pragma unroll
    for (int kk = 0; kk < 8; ++kk) {
#pragma unroll
      for (int n = 0; n < 16; ++n) {
        s16x8 bf = WB[(size_t)m * 8192 + (kk * 16 + n) * 64 + l];
        acc[n] = MFMA_BF16(af[kk], bf, acc[n]);
      }
    }
    const float scale = (m < 2) ? -L2E : 1.0f;   // pre-scale z,r by -log2(e)
#pragma unroll
    for (int n = 0; n < 16; ++n) {
      int col = n * 16 + (l & 15);
      float b = wbias[m * 256 + col];
      float v0 = (acc[n][0] + b) * scale;
      float v1 = (acc[n][1] + b) * scale;
      float v2 = (acc[n][2] + b) * scale;
      float v3 = (acc[n][3] + b) * scale;
      uint32_t w0 = cvt_pk_bf16(v0, v1);
      uint32_t w1 = cvt_pk_bf16(v2, v3);
      size_t idx = ((((size_t)m * 1024 + t) * 4 + g) * 16 + n) * 64 + l;
      ((uint64_t*)xout)[idx] = (uint64_t)w0 | ((uint64_t)w1 << 32);
    }
  }
}

__global__ __launch_bounds__(512, 2) void k_rnn(
    const u16* __restrict__ wfrag, const u16* __restrict__ xin,
    const float* __restrict__ h0, const float* __restrict__ ch,
    float* __restrict__ out)
{
  __shared__ __align__(16) u16 hb[2][512];   // 2 x 1 KiB: rows 0-1, idx r*256+f

  const int blk = blockIdx.x;           // 0..31 ; batches 2*blk, 2*blk+1
  const int tid = threadIdx.x;
  const int l   = tid & 63;
  const int w   = tid >> 6;             // wave 0..7 owns cols [32w, 32w+32)
  const int col16 = l & 15;
  const int nt    = (l >> 4) & 1;       // lane's n-tile within wave
  const int rg    = l >> 5;             // lane's batch row 0/1
  const int cgate = w * 32 + nt * 16 + col16;
  const int b     = 2 * blk + rg;       // lane's output batch

  const s16x8* WB = (const s16x8*)wfrag;

  // All three U-mat B-frags for n-tiles 2w, 2w+1 (48 s16x8 -> AGPRs)
  s16x8 BZ[2][8], BR[2][8], BH[2][8];
#pragma unroll
  for (int q = 0; q < 2; ++q) {
    int n = 2 * w + q;
#pragma unroll
    for (int kk = 0; kk < 8; ++kk) {
      BZ[q][kk] = WB[(size_t)3 * 8192 + (kk * 16 + n) * 64 + l];
      BR[q][kk] = WB[(size_t)4 * 8192 + (kk * 16 + n) * 64 + l];
      BH[q][kk] = WB[(size_t)5 * 8192 + (kk * 16 + n) * 64 + l];
    }
  }

  const float chv = ch[cgate];
  float hp = h0[(size_t)b * 256 + cgate];

  // seed hb[0]: 512 threads cover 2 rows x 256 features
  hb[0][tid] = f2bf(h0[(size_t)(2 * blk + (tid >> 8)) * 256 + (tid & 255)]);
  __syncthreads();

  char* hbbase = (char*)&hb[0][0];
  const int rd_off = (col16 & 1) * 512 + (l >> 4) * 16;   // + kk*64 + hoff
  const int wb_off = rg * 512 + cgate * 2;

  // x u32-pair loads: value pair (batches 2blk,2blk+1) for (m, col cgate)
  const uint32_t* x32 = (const uint32_t*)xin;
  const int n_ = 2 * w + nt;
  uint32_t xo = (uint32_t)(((blk >> 3) * 16 + n_) * 64 + ((blk & 7) >> 1) * 16 + col16) * 2u
              + (uint32_t)(blk & 1);
  const uint32_t XM = 8388608u;        // m-stride in u32; t-stride = 8192
  uint32_t oo = (uint32_t)b * 262144u + (uint32_t)cgate;

  // prefetch t=0
  uint32_t nx0 = x32[xo], nx1 = x32[xo + XM], nx2 = x32[xo + 2u * XM];

  int hoff = 0;
  const uint32_t xsel = rg ? 0xffff0000u : 0u;   // hi/lo half select mask base

  for (int t = 0; t < 1024; ++t) {
    uint32_t cx0 = nx0, cx1 = nx1, cx2 = nx2;
    xo += (t < 1023) ? 8192u : 0u;
    nx0 = x32[xo]; nx1 = x32[xo + XM]; nx2 = x32[xo + 2u * XM];

    const char* rdp = hbbase + hoff + rd_off;

    // ---- MFMA: 3 mats x 2 n-tiles x 8 kk, parity-mirror broadcast reads ----
    f32x4 az0 = 0.0f, az1 = 0.0f, ar0 = 0.0f, ar1 = 0.0f, ah0 = 0.0f, ah1 = 0.0f;
#pragma unroll
    for (int kk = 0; kk < 8; ++kk) {
      s16x8 a_ = *(const s16x8*)(rdp + kk * 64);
      az0 = MFMA_BF16(a_, BZ[0][kk], az0);
      ar0 = MFMA_BF16(a_, BR[0][kk], ar0);
      ah0 = MFMA_BF16(a_, BH[0][kk], ah0);
      az1 = MFMA_BF16(a_, BZ[1][kk], az1);
      ar1 = MFMA_BF16(a_, BR[1][kk], ar1);
      ah1 = MFMA_BF16(a_, BH[1][kk], ah1);
    }

    // ---- per-lane select: tile nt (cndmask), then batch reg rg (cndmask) ----
    float vz = rg ? (nt ? az1[1] : az0[1]) : (nt ? az1[0] : az0[0]);
    float vr = rg ? (nt ? ar1[1] : ar0[1]) : (nt ? ar1[0] : ar0[0]);
    float vh = rg ? (nt ? ah1[1] : ah0[1]) : (nt ? ah1[0] : ah0[0]);

    // ---- gate: exactly 1 output per lane, no divergence ----
    float xz = __uint_as_float(rg ? (cx0 & xsel) : (cx0 << 16));
    float xr = __uint_as_float(rg ? (cx1 & xsel) : (cx1 << 16));
    float xh = __uint_as_float(rg ? (cx2 & xsel) : (cx2 << 16));

    float z_  = fast_rcp(1.0f + fast_exp2(fmaf(vz, -L2E, xz)));
    float rgt = fast_rcp(1.0f + fast_exp2(fmaf(vr, -L2E, xr)));
    float th  = tanh_(fmaf(rgt, vh + chv, xh));
    float hn  = fmaf(z_, hp - th, th);
    hp = hn;

    // next-step h write + output store (store stays in flight)
    *(u16*)(hbbase + (hoff ^ 1024) + wb_off) = f2bf(hn);
    out[oo] = hn;
    oo += 256u;

    hoff ^= 1024;
    // light barrier: LDS ordering only; do NOT drain vmcnt
    asm volatile("s_waitcnt lgkmcnt(0)" ::: "memory");
    __builtin_amdgcn_s_barrier();
  }

  // h_last
  out[16777216u + (uint32_t)b * 256u + (uint32_t)cgate] = hp;
}

extern "C" void kernel_launch(void* const* d_in, const int* in_sizes, int n_in,
                              void* d_out, int out_size, void* d_ws, size_t ws_size,
                              hipStream_t stream) {
  const float* X  = (const float*)d_in[0];
  const float* h0 = (const float*)d_in[1];
  const float* Wz = (const float*)d_in[2];
  const float* Wr = (const float*)d_in[3];
  const float* Wh = (const float*)d_in[4];
  const float* bz = (const float*)d_in[5];
  const float* br = (const float*)d_in[6];
  const float* bh = (const float*)d_in[7];
  const float* Uz = (const float*)d_in[8];
  const float* Ur = (const float*)d_in[9];
  const float* Uh = (const float*)d_in[10];
  const float* cz = (const float*)d_in[11];
  const float* cr = (const float*)d_in[12];
  const float* ch = (const float*)d_in[13];

  char*  ws    = (char*)d_ws;
  u16*   wfrag = (u16*)ws;
  float* wbias = (float*)(ws + WS_BIAS_OFF);
  u16*   xbuf  = (u16*)(ws + WS_X_OFF);
  float* out   = (float*)d_out;

  k_prep<<<193, 256, 0, stream>>>(Wz, Wr, Wh, Uz, Ur, Uh, bz, br, bh, cz, cr, ch,
                                  wfrag, wbias);
  k_proj<<<1024, 256, 0, stream>>>(X, wfrag, wbias, xbuf);
  k_rnn<<<32, 512, 0, stream>>>(wfrag, xbuf, h0, ch, out);
}

// Round 10
// 1000.839 us; speedup vs baseline: 1.7705x; 1.1367x over previous
//
#include <hip/hip_runtime.h>
#include <stdint.h>

// GRU: B=64, T=1024, I=256, H=256, fp32 in/out, bf16 MFMA compute.
// k_prep: fragmentize 6 weight mats into MFMA B-frag layout; fold biases.
// k_proj: x_m = X@W_m + b'_m (z,r pre-scaled by -log2 e). 8 waves/block:
//         wave = (batch-half p, n-quad q); B-frags reused across 2 M-tiles
//         -> 4x less B traffic than the 16-nt/wave version.
// k_rnn : 32 blocks x 512 thr (8 waves, 2/SIMD); 2 batches/block.
//         Parity-mirror A-reads (R9-proven, bank-free broadcast); all 3 U
//         mats in regs/AGPRs; uniform 1 gate/lane via cndmask select.
//         MAT-PHASED schedule: A-frags once -> Z MFMAs -> z-chain -> R MFMAs
//         -> r-chain -> H MFMAs -> tanh tail; z/r transcendentals hide under
//         the following MFMA phases. cvt_pk for the critical h-write.
//         Light barrier (lgkmcnt-only); x as u32 pairs prefetched 1 ahead.

typedef float  f32x4 __attribute__((ext_vector_type(4)));
typedef short  s16x8 __attribute__((ext_vector_type(8)));
typedef unsigned short u16;

#define MFMA_BF16(a, b, c) __builtin_amdgcn_mfma_f32_16x16x32_bf16((a), (b), (c), 0, 0, 0)
#define L2E 1.4426950408889634f

static __device__ __forceinline__ u16 f2bf(float f) {
  uint32_t u = __float_as_uint(f);
  u += 0x7FFFu + ((u >> 16) & 1u);   // RNE
  return (u16)(u >> 16);
}
static __device__ __forceinline__ uint32_t cvt_pk_bf16(float lo, float hi) {
  uint32_t r;
  asm("v_cvt_pk_bf16_f32 %0, %1, %2" : "=v"(r) : "v"(lo), "v"(hi));
  return r;
}
static __device__ __forceinline__ float fast_exp2(float x) {
#if __has_builtin(__builtin_amdgcn_exp2f)
  return __builtin_amdgcn_exp2f(x);
#else
  return exp2f(x);
#endif
}
static __device__ __forceinline__ float fast_rcp(float x) {
#if __has_builtin(__builtin_amdgcn_rcpf)
  return __builtin_amdgcn_rcpf(x);
#else
  return 1.0f / x;
#endif
}
static __device__ __forceinline__ float tanh_(float x) {
  float ax = fabsf(x);
  float e  = fast_exp2(-2.885390081777927f * ax);   // exp(-2|x|)
  float r  = (1.0f - e) * fast_rcp(1.0f + e);
  return x < 0.0f ? -r : r;
}

// ---- ws layout (bytes) ----
// [0, 786432)          : 6 mats x 8kk x 16n x 64lane x 16B bf16 B-fragments
// [786432, 789504)     : folded biases, 3 x 256 fp32 (unscaled)
// [1MiB, 1MiB + 96MiB) : x projections bf16, [m][t][g][n][lane][j] u16
#define WS_BIAS_OFF  786432
#define WS_X_OFF     (1u << 20)

// Fragment convention: kappa(l,i) = (l>>4)*8 + i.
// B-frag (mat,kk,n): lane l slot i = M[32kk + kappa(l,i)][16n + (l&15)]
// A-frag (kk):       lane l slot i = A[l&15][32kk + kappa(l,i)]
// C/D: col = lane&15, row = (lane>>4)*4 + reg   [m89]
// hb (rows 0-1, 1KB/buf): u16 idx = r*256 + f.
//   A-read lane l: 16B at (col16&1)*512 + (l>>4)*16 + kk*64
//   -> A[i] = h[i&1]; D reg j = batch (j&1) preact at col l&15.

__global__ __launch_bounds__(256) void k_prep(
    const float* __restrict__ Wz, const float* __restrict__ Wr, const float* __restrict__ Wh,
    const float* __restrict__ Uz, const float* __restrict__ Ur, const float* __restrict__ Uh,
    const float* __restrict__ bz, const float* __restrict__ br, const float* __restrict__ bh,
    const float* __restrict__ cz, const float* __restrict__ cr, const float* __restrict__ ch,
    u16* __restrict__ wfrag, float* __restrict__ wbias)
{
  if (blockIdx.x == 192) {   // bias fold block
    int c = threadIdx.x;
    wbias[c]       = bz[c] + cz[c];
    wbias[256 + c] = br[c] + cr[c];
    wbias[512 + c] = bh[c];
    return;
  }
  int tid = blockIdx.x * 256 + threadIdx.x;      // 0..49151
  int mat = tid >> 13;                           // 6 mats x 8192 threads
  int kk  = (tid >> 10) & 7;
  int n   = (tid >> 6) & 15;
  int l   = tid & 63;
  const float* M = (mat == 0) ? Wz : (mat == 1) ? Wr : (mat == 2) ? Wh
                 : (mat == 3) ? Uz : (mat == 4) ? Ur : Uh;
  int col   = n * 16 + (l & 15);
  int kbase = kk * 32 + (l >> 4) * 8;
  uint32_t d[4];
#pragma unroll
  for (int p = 0; p < 4; ++p) {
    u16 lo = f2bf(M[(kbase + 2 * p    ) * 256 + col]);
    u16 hi = f2bf(M[(kbase + 2 * p + 1) * 256 + col]);
    d[p] = (uint32_t)lo | ((uint32_t)hi << 16);
  }
  uint32_t* dst = (uint32_t*)(wfrag + ((size_t)mat * 65536 + (size_t)((kk * 16 + n) * 64 + l) * 8));
  dst[0] = d[0]; dst[1] = d[1]; dst[2] = d[2]; dst[3] = d[3];
}

__global__ __launch_bounds__(512) void k_proj(
    const float* __restrict__ X, const u16* __restrict__ wfrag,
    const float* __restrict__ wbias, u16* __restrict__ xout)
{
  const int t   = blockIdx.x;
  const int tid = threadIdx.x;
  const int l   = tid & 63;
  const int w   = tid >> 6;        // wave 0..7
  const int p   = w >> 2;          // batch half: rows 32p..32p+31
  const int q   = w & 3;           // n-quad: n-tiles 4q..4q+3

  // A-fragments for 2 M-tiles, resident (64 VGPR)
  s16x8 af[2][8];
#pragma unroll
  for (int mti = 0; mti < 2; ++mti) {
    const float* xrow = X + ((size_t)((2 * p + mti) * 16 + (l & 15)) * 1024 + t) * 256
                        + (l >> 4) * 8;
#pragma unroll
    for (int kk = 0; kk < 8; ++kk) {
      f32x4 a0 = *(const f32x4*)(xrow + kk * 32);
      f32x4 a1 = *(const f32x4*)(xrow + kk * 32 + 4);
      union { uint32_t d[4]; s16x8 v; } U;
      U.d[0] = cvt_pk_bf16(a0[0], a0[1]);
      U.d[1] = cvt_pk_bf16(a0[2], a0[3]);
      U.d[2] = cvt_pk_bf16(a1[0], a1[1]);
      U.d[3] = cvt_pk_bf16(a1[2], a1[3]);
      af[mti][kk] = U.v;
    }
  }

  const s16x8* WB = (const s16x8*)wfrag;
#pragma unroll
  for (int m = 0; m < 3; ++m) {
    f32x4 acc[2][4];
#pragma unroll
    for (int mti = 0; mti < 2; ++mti)
#pragma unroll
      for (int nti = 0; nti < 4; ++nti) acc[mti][nti] = 0.0f;
#pragma unroll
    for (int kk = 0; kk < 8; ++kk) {
#pragma unroll
      for (int nti = 0; nti < 4; ++nti) {
        s16x8 bf = WB[(size_t)m * 8192 + (kk * 16 + 4 * q + nti) * 64 + l];
        acc[0][nti] = MFMA_BF16(af[0][kk], bf, acc[0][nti]);
        acc[1][nti] = MFMA_BF16(af[1][kk], bf, acc[1][nti]);
      }
    }
    const float scale = (m < 2) ? -L2E : 1.0f;   // pre-scale z,r by -log2(e)
#pragma unroll
    for (int mti = 0; mti < 2; ++mti) {
#pragma unroll
      for (int nti = 0; nti < 4; ++nti) {
        int n   = 4 * q + nti;
        int col = n * 16 + (l & 15);
        float b = wbias[m * 256 + col];
        float v0 = (acc[mti][nti][0] + b) * scale;
        float v1 = (acc[mti][nti][1] + b) * scale;
        float v2 = (acc[mti][nti][2] + b) * scale;
        float v3 = (acc[mti][nti][3] + b) * scale;
        uint32_t w0 = cvt_pk_bf16(v0, v1);
        uint32_t w1 = cvt_pk_bf16(v2, v3);
        size_t idx = ((((size_t)m * 1024 + t) * 4 + (2 * p + mti)) * 16 + n) * 64 + l;
        ((uint64_t*)xout)[idx] = (uint64_t)w0 | ((uint64_t)w1 << 32);
      }
    }
  }
}

__global__ __launch_bounds__(512, 2) void k_rnn(
    const u16* __restrict__ wfrag, const u16* __restrict__ xin,
    const float* __restrict__ h0, const float* __restrict__ ch,
    float* __restrict__ out)
{
  __shared__ __align__(16) u16 hb[2][512];   // 2 x 1 KiB: rows 0-1, idx r*256+f

  const int blk = blockIdx.x;           // 0..31 ; batches 2*blk, 2*blk+1
  const int tid = threadIdx.x;
  const int l   = tid & 63;
  const int w   = tid >> 6;             // wave 0..7 owns cols [32w, 32w+32)
  const int col16 = l & 15;
  const int nt    = (l >> 4) & 1;       // lane's n-tile within wave
  const int rg    = l >> 5;             // lane's batch row 0/1
  const int cgate = w * 32 + nt * 16 + col16;
  const int b     = 2 * blk + rg;       // lane's output batch

  const s16x8* WB = (const s16x8*)wfrag;

  // All three U-mat B-frags for n-tiles 2w, 2w+1 (48 s16x8 -> AGPRs)
  s16x8 BZ[2][8], BR[2][8], BH[2][8];
#pragma unroll
  for (int q = 0; q < 2; ++q) {
    int n = 2 * w + q;
#pragma unroll
    for (int kk = 0; kk < 8; ++kk) {
      BZ[q][kk] = WB[(size_t)3 * 8192 + (kk * 16 + n) * 64 + l];
      BR[q][kk] = WB[(size_t)4 * 8192 + (kk * 16 + n) * 64 + l];
      BH[q][kk] = WB[(size_t)5 * 8192 + (kk * 16 + n) * 64 + l];
    }
  }

  const float chv = ch[cgate];
  float hp = h0[(size_t)b * 256 + cgate];

  // seed hb[0]: 512 threads cover 2 rows x 256 features
  hb[0][tid] = f2bf(h0[(size_t)(2 * blk + (tid >> 8)) * 256 + (tid & 255)]);
  __syncthreads();

  char* hbbase = (char*)&hb[0][0];
  const int rd_off = (col16 & 1) * 512 + (l >> 4) * 16;   // + kk*64 + hoff
  const int wb_off = rg * 512 + cgate * 2;

  // x u32-pair loads: value pair (batches 2blk,2blk+1) for (m, col cgate)
  const uint32_t* x32 = (const uint32_t*)xin;
  const int n_ = 2 * w + nt;
  uint32_t xo = (uint32_t)(((blk >> 3) * 16 + n_) * 64 + ((blk & 7) >> 1) * 16 + col16) * 2u
              + (uint32_t)(blk & 1);
  const uint32_t XM = 8388608u;        // m-stride in u32; t-stride = 8192
  uint32_t oo = (uint32_t)b * 262144u + (uint32_t)cgate;

  // prefetch t=0
  uint32_t nx0 = x32[xo], nx1 = x32[xo + XM], nx2 = x32[xo + 2u * XM];

  int hoff = 0;
  const uint32_t xsel = rg ? 0xffff0000u : 0u;   // hi/lo half select mask

  for (int t = 0; t < 1024; ++t) {
    uint32_t cx0 = nx0, cx1 = nx1, cx2 = nx2;
    xo += (t < 1023) ? 8192u : 0u;
    nx0 = x32[xo]; nx1 = x32[xo + XM]; nx2 = x32[xo + 2u * XM];

    const char* rdp = hbbase + hoff + rd_off;

    // ---- A-frags once (8 broadcast ds_read_b128, parity-mirror) ----
    s16x8 a_[8];
#pragma unroll
    for (int kk = 0; kk < 8; ++kk) a_[kk] = *(const s16x8*)(rdp + kk * 64);

    // ---- Z phase: 16 MFMA, then z-chain (hides under R/H phases) ----
    f32x4 az0 = 0.0f, az1 = 0.0f;
#pragma unroll
    for (int kk = 0; kk < 8; ++kk) {
      az0 = MFMA_BF16(a_[kk], BZ[0][kk], az0);
      az1 = MFMA_BF16(a_[kk], BZ[1][kk], az1);
    }
    float vz = rg ? (nt ? az1[1] : az0[1]) : (nt ? az1[0] : az0[0]);
    float xz = __uint_as_float(rg ? (cx0 & xsel) : (cx0 << 16));
    float z_ = fast_rcp(1.0f + fast_exp2(fmaf(vz, -L2E, xz)));

    // ---- R phase ----
    f32x4 ar0 = 0.0f, ar1 = 0.0f;
#pragma unroll
    for (int kk = 0; kk < 8; ++kk) {
      ar0 = MFMA_BF16(a_[kk], BR[0][kk], ar0);
      ar1 = MFMA_BF16(a_[kk], BR[1][kk], ar1);
    }
    float vr  = rg ? (nt ? ar1[1] : ar0[1]) : (nt ? ar1[0] : ar0[0]);
    float xr  = __uint_as_float(rg ? (cx1 & xsel) : (cx1 << 16));
    float rgt = fast_rcp(1.0f + fast_exp2(fmaf(vr, -L2E, xr)));

    // ---- H phase ----
    f32x4 ah0 = 0.0f, ah1 = 0.0f;
#pragma unroll
    for (int kk = 0; kk < 8; ++kk) {
      ah0 = MFMA_BF16(a_[kk], BH[0][kk], ah0);
      ah1 = MFMA_BF16(a_[kk], BH[1][kk], ah1);
    }
    float vh = rg ? (nt ? ah1[1] : ah0[1]) : (nt ? ah1[0] : ah0[0]);
    float xh = __uint_as_float(rg ? (cx2 & xsel) : (cx2 << 16));

    // ---- exposed tail: tanh + combine + h-write ----
    float th = tanh_(fmaf(rgt, vh + chv, xh));
    float hn = fmaf(z_, hp - th, th);
    hp = hn;

    uint32_t pk = cvt_pk_bf16(hn, hn);
    *(u16*)(hbbase + (hoff ^ 1024) + wb_off) = (u16)pk;
    out[oo] = hn;
    oo += 256u;

    hoff ^= 1024;
    // light barrier: LDS ordering only; do NOT drain vmcnt
    asm volatile("s_waitcnt lgkmcnt(0)" ::: "memory");
    __builtin_amdgcn_s_barrier();
  }

  // h_last
  out[16777216u + (uint32_t)b * 256u + (uint32_t)cgate] = hp;
}

extern "C" void kernel_launch(void* const* d_in, const int* in_sizes, int n_in,
                              void* d_out, int out_size, void* d_ws, size_t ws_size,
                              hipStream_t stream) {
  const float* X  = (const float*)d_in[0];
  const float* h0 = (const float*)d_in[1];
  const float* Wz = (const float*)d_in[2];
  const float* Wr = (const float*)d_in[3];
  const float* Wh = (const float*)d_in[4];
  const float* bz = (const float*)d_in[5];
  const float* br = (const float*)d_in[6];
  const float* bh = (const float*)d_in[7];
  const float* Uz = (const float*)d_in[8];
  const float* Ur = (const float*)d_in[9];
  const float* Uh = (const float*)d_in[10];
  const float* cz = (const float*)d_in[11];
  const float* cr = (const float*)d_in[12];
  const float* ch = (const float*)d_in[13];

  char*  ws    = (char*)d_ws;
  u16*   wfrag = (u16*)ws;
  float* wbias = (float*)(ws + WS_BIAS_OFF);
  u16*   xbuf  = (u16*)(ws + WS_X_OFF);
  float* out   = (float*)d_out;

  k_prep<<<193, 256, 0, stream>>>(Wz, Wr, Wh, Uz, Ur, Uh, bz, br, bh, cz, cr, ch,
                                  wfrag, wbias);
  k_proj<<<1024, 512, 0, stream>>>(X, wfrag, wbias, xbuf);
  k_rnn<<<32, 512, 0, stream>>>(wfrag, xbuf, h0, ch, out);
}

// Round 11
// 996.291 us; speedup vs baseline: 1.7785x; 1.0046x over previous
//
#include <hip/hip_runtime.h>
#include <stdint.h>

// GRU: B=64, T=1024, I=256, H=256, fp32 in/out, bf16 MFMA compute.
// k_prep: fragmentize 6 weight mats into MFMA B-frag layout; fold biases.
// k_proj: x_m = X@W_m + b'_m (z,r pre-scaled by -log2 e). 8 waves/block:
//         wave = (batch-half p, n-quad q); B-frags reused across 2 M-tiles.
// k_rnn : 32 blocks x 512 thr (8 waves, 2/SIMD); 2 batches/block.
//         Parity-mirror A-reads (bank-free broadcast); all 3 U mats in
//         regs/AGPRs; uniform 1 gate/lane via cndmask select.
//         PHASE ORDER (R11): R+H interleaved (32 MFMA, 4 chains) ->
//         r-sigmoid + tanh -> Z phase (16 MFMA; tanh retires under it) ->
//         z-sigmoid + blend. Tail exposed after last MFMA = ~60 cyc.
//         Light barrier (lgkmcnt-only); x as u32 pairs prefetched 1 ahead.

typedef float  f32x4 __attribute__((ext_vector_type(4)));
typedef short  s16x8 __attribute__((ext_vector_type(8)));
typedef unsigned short u16;

#define MFMA_BF16(a, b, c) __builtin_amdgcn_mfma_f32_16x16x32_bf16((a), (b), (c), 0, 0, 0)
#define L2E 1.4426950408889634f

static __device__ __forceinline__ u16 f2bf(float f) {
  uint32_t u = __float_as_uint(f);
  u += 0x7FFFu + ((u >> 16) & 1u);   // RNE
  return (u16)(u >> 16);
}
static __device__ __forceinline__ uint32_t cvt_pk_bf16(float lo, float hi) {
  uint32_t r;
  asm("v_cvt_pk_bf16_f32 %0, %1, %2" : "=v"(r) : "v"(lo), "v"(hi));
  return r;
}
static __device__ __forceinline__ float fast_exp2(float x) {
#if __has_builtin(__builtin_amdgcn_exp2f)
  return __builtin_amdgcn_exp2f(x);
#else
  return exp2f(x);
#endif
}
static __device__ __forceinline__ float fast_rcp(float x) {
#if __has_builtin(__builtin_amdgcn_rcpf)
  return __builtin_amdgcn_rcpf(x);
#else
  return 1.0f / x;
#endif
}
static __device__ __forceinline__ float tanh_(float x) {
  float ax = fabsf(x);
  float e  = fast_exp2(-2.885390081777927f * ax);   // exp(-2|x|)
  float r  = (1.0f - e) * fast_rcp(1.0f + e);
  return x < 0.0f ? -r : r;
}

// ---- ws layout (bytes) ----
// [0, 786432)          : 6 mats x 8kk x 16n x 64lane x 16B bf16 B-fragments
// [786432, 789504)     : folded biases, 3 x 256 fp32 (unscaled)
// [1MiB, 1MiB + 96MiB) : x projections bf16, [m][t][g][n][lane][j] u16
#define WS_BIAS_OFF  786432
#define WS_X_OFF     (1u << 20)

// Fragment convention: kappa(l,i) = (l>>4)*8 + i.
// B-frag (mat,kk,n): lane l slot i = M[32kk + kappa(l,i)][16n + (l&15)]
// A-frag (kk):       lane l slot i = A[l&15][32kk + kappa(l,i)]
// C/D: col = lane&15, row = (lane>>4)*4 + reg   [m89]
// hb (rows 0-1, 1KB/buf): u16 idx = r*256 + f.
//   A-read lane l: 16B at (col16&1)*512 + (l>>4)*16 + kk*64
//   -> A[i] = h[i&1]; D reg j = batch (j&1) preact at col l&15.

__global__ __launch_bounds__(256) void k_prep(
    const float* __restrict__ Wz, const float* __restrict__ Wr, const float* __restrict__ Wh,
    const float* __restrict__ Uz, const float* __restrict__ Ur, const float* __restrict__ Uh,
    const float* __restrict__ bz, const float* __restrict__ br, const float* __restrict__ bh,
    const float* __restrict__ cz, const float* __restrict__ cr, const float* __restrict__ ch,
    u16* __restrict__ wfrag, float* __restrict__ wbias)
{
  if (blockIdx.x == 192) {   // bias fold block
    int c = threadIdx.x;
    wbias[c]       = bz[c] + cz[c];
    wbias[256 + c] = br[c] + cr[c];
    wbias[512 + c] = bh[c];
    return;
  }
  int tid = blockIdx.x * 256 + threadIdx.x;      // 0..49151
  int mat = tid >> 13;                           // 6 mats x 8192 threads
  int kk  = (tid >> 10) & 7;
  int n   = (tid >> 6) & 15;
  int l   = tid & 63;
  const float* M = (mat == 0) ? Wz : (mat == 1) ? Wr : (mat == 2) ? Wh
                 : (mat == 3) ? Uz : (mat == 4) ? Ur : Uh;
  int col   = n * 16 + (l & 15);
  int kbase = kk * 32 + (l >> 4) * 8;
  uint32_t d[4];
#pragma unroll
  for (int p = 0; p < 4; ++p) {
    u16 lo = f2bf(M[(kbase + 2 * p    ) * 256 + col]);
    u16 hi = f2bf(M[(kbase + 2 * p + 1) * 256 + col]);
    d[p] = (uint32_t)lo | ((uint32_t)hi << 16);
  }
  uint32_t* dst = (uint32_t*)(wfrag + ((size_t)mat * 65536 + (size_t)((kk * 16 + n) * 64 + l) * 8));
  dst[0] = d[0]; dst[1] = d[1]; dst[2] = d[2]; dst[3] = d[3];
}

__global__ __launch_bounds__(512) void k_proj(
    const float* __restrict__ X, const u16* __restrict__ wfrag,
    const float* __restrict__ wbias, u16* __restrict__ xout)
{
  const int t   = blockIdx.x;
  const int tid = threadIdx.x;
  const int l   = tid & 63;
  const int w   = tid >> 6;        // wave 0..7
  const int p   = w >> 2;          // batch half: rows 32p..32p+31
  const int q   = w & 3;           // n-quad: n-tiles 4q..4q+3

  // A-fragments for 2 M-tiles, resident (64 VGPR)
  s16x8 af[2][8];
#pragma unroll
  for (int mti = 0; mti < 2; ++mti) {
    const float* xrow = X + ((size_t)((2 * p + mti) * 16 + (l & 15)) * 1024 + t) * 256
                        + (l >> 4) * 8;
#pragma unroll
    for (int kk = 0; kk < 8; ++kk) {
      f32x4 a0 = *(const f32x4*)(xrow + kk * 32);
      f32x4 a1 = *(const f32x4*)(xrow + kk * 32 + 4);
      union { uint32_t d[4]; s16x8 v; } U;
      U.d[0] = cvt_pk_bf16(a0[0], a0[1]);
      U.d[1] = cvt_pk_bf16(a0[2], a0[3]);
      U.d[2] = cvt_pk_bf16(a1[0], a1[1]);
      U.d[3] = cvt_pk_bf16(a1[2], a1[3]);
      af[mti][kk] = U.v;
    }
  }

  const s16x8* WB = (const s16x8*)wfrag;
#pragma unroll
  for (int m = 0; m < 3; ++m) {
    f32x4 acc[2][4];
#pragma unroll
    for (int mti = 0; mti < 2; ++mti)
#pragma unroll
      for (int nti = 0; nti < 4; ++nti) acc[mti][nti] = 0.0f;
#pragma unroll
    for (int kk = 0; kk < 8; ++kk) {
#pragma unroll
      for (int nti = 0; nti < 4; ++nti) {
        s16x8 bf = WB[(size_t)m * 8192 + (kk * 16 + 4 * q + nti) * 64 + l];
        acc[0][nti] = MFMA_BF16(af[0][kk], bf, acc[0][nti]);
        acc[1][nti] = MFMA_BF16(af[1][kk], bf, acc[1][nti]);
      }
    }
    const float scale = (m < 2) ? -L2E : 1.0f;   // pre-scale z,r by -log2(e)
#pragma unroll
    for (int mti = 0; mti < 2; ++mti) {
#pragma unroll
      for (int nti = 0; nti < 4; ++nti) {
        int n   = 4 * q + nti;
        int col = n * 16 + (l & 15);
        float b = wbias[m * 256 + col];
        float v0 = (acc[mti][nti][0] + b) * scale;
        float v1 = (acc[mti][nti][1] + b) * scale;
        float v2 = (acc[mti][nti][2] + b) * scale;
        float v3 = (acc[mti][nti][3] + b) * scale;
        uint32_t w0 = cvt_pk_bf16(v0, v1);
        uint32_t w1 = cvt_pk_bf16(v2, v3);
        size_t idx = ((((size_t)m * 1024 + t) * 4 + (2 * p + mti)) * 16 + n) * 64 + l;
        ((uint64_t*)xout)[idx] = (uint64_t)w0 | ((uint64_t)w1 << 32);
      }
    }
  }
}

__global__ __launch_bounds__(512, 2) void k_rnn(
    const u16* __restrict__ wfrag, const u16* __restrict__ xin,
    const float* __restrict__ h0, const float* __restrict__ ch,
    float* __restrict__ out)
{
  __shared__ __align__(16) u16 hb[2][512];   // 2 x 1 KiB: rows 0-1, idx r*256+f

  const int blk = blockIdx.x;           // 0..31 ; batches 2*blk, 2*blk+1
  const int tid = threadIdx.x;
  const int l   = tid & 63;
  const int w   = tid >> 6;             // wave 0..7 owns cols [32w, 32w+32)
  const int col16 = l & 15;
  const int nt    = (l >> 4) & 1;       // lane's n-tile within wave
  const int rg    = l >> 5;             // lane's batch row 0/1
  const int cgate = w * 32 + nt * 16 + col16;
  const int b     = 2 * blk + rg;       // lane's output batch

  const s16x8* WB = (const s16x8*)wfrag;

  // All three U-mat B-frags for n-tiles 2w, 2w+1 (48 s16x8 -> AGPRs)
  s16x8 BZ[2][8], BR[2][8], BH[2][8];
#pragma unroll
  for (int q = 0; q < 2; ++q) {
    int n = 2 * w + q;
#pragma unroll
    for (int kk = 0; kk < 8; ++kk) {
      BZ[q][kk] = WB[(size_t)3 * 8192 + (kk * 16 + n) * 64 + l];
      BR[q][kk] = WB[(size_t)4 * 8192 + (kk * 16 + n) * 64 + l];
      BH[q][kk] = WB[(size_t)5 * 8192 + (kk * 16 + n) * 64 + l];
    }
  }

  const float chv = ch[cgate];
  float hp = h0[(size_t)b * 256 + cgate];

  // seed hb[0]: 512 threads cover 2 rows x 256 features
  hb[0][tid] = f2bf(h0[(size_t)(2 * blk + (tid >> 8)) * 256 + (tid & 255)]);
  __syncthreads();

  char* hbbase = (char*)&hb[0][0];
  const int rd_off = (col16 & 1) * 512 + (l >> 4) * 16;   // + kk*64 + hoff
  const int wb_off = rg * 512 + cgate * 2;

  // x u32-pair loads: value pair (batches 2blk,2blk+1) for (m, col cgate)
  const uint32_t* x32 = (const uint32_t*)xin;
  const int n_ = 2 * w + nt;
  uint32_t xo = (uint32_t)(((blk >> 3) * 16 + n_) * 64 + ((blk & 7) >> 1) * 16 + col16) * 2u
              + (uint32_t)(blk & 1);
  const uint32_t XM = 8388608u;        // m-stride in u32; t-stride = 8192
  uint32_t oo = (uint32_t)b * 262144u + (uint32_t)cgate;

  // prefetch t=0
  uint32_t nx0 = x32[xo], nx1 = x32[xo + XM], nx2 = x32[xo + 2u * XM];

  int hoff = 0;
  const uint32_t xsel = rg ? 0xffff0000u : 0u;   // hi/lo half select mask

  for (int t = 0; t < 1024; ++t) {
    uint32_t cx0 = nx0, cx1 = nx1, cx2 = nx2;
    xo += (t < 1023) ? 8192u : 0u;
    nx0 = x32[xo]; nx1 = x32[xo + XM]; nx2 = x32[xo + 2u * XM];

    const char* rdp = hbbase + hoff + rd_off;

    // ---- A-frags once (8 broadcast ds_read_b128, parity-mirror) ----
    s16x8 a_[8];
#pragma unroll
    for (int kk = 0; kk < 8; ++kk) a_[kk] = *(const s16x8*)(rdp + kk * 64);

    // x extracts (independent of all MFMA phases)
    float xz = __uint_as_float(rg ? (cx0 & xsel) : (cx0 << 16));
    float xr = __uint_as_float(rg ? (cx1 & xsel) : (cx1 << 16));
    float xh = __uint_as_float(rg ? (cx2 & xsel) : (cx2 << 16));

    // ---- R+H phases interleaved: 32 MFMA, 4 independent chains ----
    f32x4 ar0 = 0.0f, ar1 = 0.0f, ah0 = 0.0f, ah1 = 0.0f;
#pragma unroll
    for (int kk = 0; kk < 8; ++kk) {
      ar0 = MFMA_BF16(a_[kk], BR[0][kk], ar0);
      ah0 = MFMA_BF16(a_[kk], BH[0][kk], ah0);
      ar1 = MFMA_BF16(a_[kk], BR[1][kk], ar1);
      ah1 = MFMA_BF16(a_[kk], BH[1][kk], ah1);
    }

    // r-sigmoid + tanh: data-independent of Z MFMAs -> retire under Z phase
    float vr  = rg ? (nt ? ar1[1] : ar0[1]) : (nt ? ar1[0] : ar0[0]);
    float rgt = fast_rcp(1.0f + fast_exp2(fmaf(vr, -L2E, xr)));
    float vh  = rg ? (nt ? ah1[1] : ah0[1]) : (nt ? ah1[0] : ah0[0]);
    float th  = tanh_(fmaf(rgt, vh + chv, xh));

    // ---- Z phase last: 16 MFMA ----
    f32x4 az0 = 0.0f, az1 = 0.0f;
#pragma unroll
    for (int kk = 0; kk < 8; ++kk) {
      az0 = MFMA_BF16(a_[kk], BZ[0][kk], az0);
      az1 = MFMA_BF16(a_[kk], BZ[1][kk], az1);
    }
    float vz = rg ? (nt ? az1[1] : az0[1]) : (nt ? az1[0] : az0[0]);
    float z_ = fast_rcp(1.0f + fast_exp2(fmaf(vz, -L2E, xz)));

    // ---- short exposed tail: blend + h-write ----
    float hn = fmaf(z_, hp - th, th);
    hp = hn;

    uint32_t pk = cvt_pk_bf16(hn, hn);
    *(u16*)(hbbase + (hoff ^ 1024) + wb_off) = (u16)pk;
    out[oo] = hn;
    oo += 256u;

    hoff ^= 1024;
    // light barrier: LDS ordering only; do NOT drain vmcnt
    asm volatile("s_waitcnt lgkmcnt(0)" ::: "memory");
    __builtin_amdgcn_s_barrier();
  }

  // h_last
  out[16777216u + (uint32_t)b * 256u + (uint32_t)cgate] = hp;
}

extern "C" void kernel_launch(void* const* d_in, const int* in_sizes, int n_in,
                              void* d_out, int out_size, void* d_ws, size_t ws_size,
                              hipStream_t stream) {
  const float* X  = (const float*)d_in[0];
  const float* h0 = (const float*)d_in[1];
  const float* Wz = (const float*)d_in[2];
  const float* Wr = (const float*)d_in[3];
  const float* Wh = (const float*)d_in[4];
  const float* bz = (const float*)d_in[5];
  const float* br = (const float*)d_in[6];
  const float* bh = (const float*)d_in[7];
  const float* Uz = (const float*)d_in[8];
  const float* Ur = (const float*)d_in[9];
  const float* Uh = (const float*)d_in[10];
  const float* cz = (const float*)d_in[11];
  const float* cr = (const float*)d_in[12];
  const float* ch = (const float*)d_in[13];

  char*  ws    = (char*)d_ws;
  u16*   wfrag = (u16*)ws;
  float* wbias = (float*)(ws + WS_BIAS_OFF);
  u16*   xbuf  = (u16*)(ws + WS_X_OFF);
  float* out   = (float*)d_out;

  k_prep<<<193, 256, 0, stream>>>(Wz, Wr, Wh, Uz, Ur, Uh, bz, br, bh, cz, cr, ch,
                                  wfrag, wbias);
  k_proj<<<1024, 512, 0, stream>>>(X, wfrag, wbias, xbuf);
  k_rnn<<<32, 512, 0, stream>>>(wfrag, xbuf, h0, ch, out);
}